// Round 12
// baseline (106.852 us; speedup 1.0000x reference)
//
#include <hip/hip_runtime.h>
#include <hip/hip_fp16.h>

// MLPKANlayer: out[b][o] = sum_i g_n(x[b,i]), n = i*128+o,
//   g_n(x) = y_n(x)*ss_n + x*rs_n  (1->5->5->1 SiLU MLP). f32 in/out.
//
// R12 key idea: the PW-linear segment index k depends only on (b,i), NOT o.
// Wave = (fixed b, lanes over o) => x[b,i] is an s_load, index math is
// wave-uniform, and with table layout tbl[i][k][o] the 64 lanes read
// CONSECUTIVE half2 -> one coalesced 256-B load. The per-lane gather of
// R8-R11 (2048 wave-gathers/CU through LDS) disappears entirely.
//  k1 build: block = i (128 blocks, 1024 thr): lanes over k, loop o (wave-
//     uniform -> weights are s_loads); values in padded LDS; coalesced
//     half2(value, slope) writes to tbl[i][k][o].
//  k2 main: 512 blocks x 512 thr; wave = (b, o-half); 128 iters of
//     s_load + uniform index math + coalesced table load + fma_mix.
// Tails extrapolate linearly (index clamped to [0,126], fraction not).
// Harness floor ~63us (256 MiB d_ws re-poison + restores) is fixed.

constexpr int IN_SZ = 128, OUT_SZ = 128, BATCH = 2048, NSUB = IN_SZ * OUT_SZ;
constexpr int KNOTS = 128, NSEG = KNOTS - 1;
constexpr float XMIN = -5.0f, XRANGE = 10.0f;
constexpr float STEP = XRANGE / (float)NSEG;
constexpr float INVH = (float)NSEG / XRANGE;   // 12.7
constexpr float UOFF = -XMIN * INVH;           // 63.5

__device__ __forceinline__ float silu_f(float z) {
  float t = __builtin_amdgcn_exp2f(z * -1.44269504088896f);   // exp(-z)
  return z * __builtin_amdgcn_rcpf(1.0f + t);
}

// ---- k1: build tbl[i][k][o] = half2(g(x_k), g(x_{k+1})-g(x_k)) -------------
// Block = one i. Lanes over k (per-lane xk), o wave-uniform -> s_load weights.
__global__ __launch_bounds__(1024) void build_ikol(
    const float* __restrict__ w0, const float* __restrict__ b0,
    const float* __restrict__ w1, const float* __restrict__ b1,
    const float* __restrict__ w2, const float* __restrict__ b2,
    const float* __restrict__ ss, const float* __restrict__ rs,
    __half2* __restrict__ tbl) {
  __shared__ float v[KNOTS * 129];              // padded: bank = (k+o)%32
  const int tid = threadIdx.x;
  const int i   = blockIdx.x;
  const int k   = tid & (KNOTS - 1);            // per-lane knot
  const int og  = __builtin_amdgcn_readfirstlane(tid >> 7);   // 0..7 uniform

  const float xk = XMIN + (float)k * STEP;

#pragma unroll 1
  for (int j = 0; j < 16; ++j) {
    const int o = og + 8 * j;                   // wave-uniform
    const int n = i * OUT_SZ + o;               // scalar -> weights s_load
    float h1[5], h2[5];
#pragma unroll
    for (int jj = 0; jj < 5; ++jj)
      h1[jj] = silu_f(fmaf(w0[n * 5 + jj], xk, b0[n * 5 + jj]));
#pragma unroll
    for (int jj = 0; jj < 5; ++jj) {
      float z = b1[n * 5 + jj];
#pragma unroll
      for (int kk = 0; kk < 5; ++kk)
        z = fmaf(w1[n * 25 + jj * 5 + kk], h1[kk], z);
      h2[jj] = silu_f(z);
    }
    float y = b2[n];
#pragma unroll
    for (int kk = 0; kk < 5; ++kk) y = fmaf(w2[n * 5 + kk], h2[kk], y);
    v[k * 129 + o] = fmaf(y, ss[n], xk * rs[n]);
  }
  __syncthreads();

  // convert + write coalesced: idx = k*128+o, consecutive tid -> consecutive o
#pragma unroll
  for (int s = 0; s < 16; ++s) {
    const int idx = tid + 1024 * s;
    const int kk = idx >> 7, oo = idx & 127;
    const float a  = v[kk * 129 + oo];
    const float sl = (kk < NSEG) ? (v[(kk + 1) * 129 + oo] - a) : 0.0f;
    tbl[((size_t)i << 14) + idx] = __floats2half2_rn(a, sl);
  }
}

// ---- k2: main — uniform index, coalesced table reads -----------------------
__global__ __launch_bounds__(512) void mlp_scan(
    const float* __restrict__ x, const __half2* __restrict__ tbl,
    float* __restrict__ out) {
  const int tid  = threadIdx.x;
  const int wv   = __builtin_amdgcn_readfirstlane(tid >> 6);  // 0..7 uniform
  const int lane = tid & 63;
  const int b    = blockIdx.x * 4 + (wv >> 1);   // wave-uniform batch row
  const int od   = ((wv & 1) << 6) + lane;       // o = ohalf*64 + lane

  const float* __restrict__ xr = x + (size_t)b * IN_SZ;

  float acc0 = 0.0f, acc1 = 0.0f;
#pragma unroll 8
  for (int i = 0; i < IN_SZ; ++i) {
    float xv = xr[i];                            // uniform -> s_load
    float u  = fmaf(xv, INVH, UOFF);
    float fi = __builtin_amdgcn_fmed3f(floorf(u), 0.0f, (float)(NSEG - 1));
    float f  = u - fi;                           // unclamped -> extrapolate
    int k    = (int)fi;                          // wave-uniform
    __half2 h = tbl[((size_t)((i << 7) + k) << 7) + od];  // coalesced 256 B
    float t = fmaf(__half2float(__high2half(h)), f,
                   __half2float(__low2half(h)));          // v_fma_mix
    if (i & 1) acc1 += t; else acc0 += t;
  }
  out[(size_t)b * OUT_SZ + od] = acc0 + acc1;
}

// ---- fallback (ws too small): exact raw-array kernel -----------------------
__global__ __launch_bounds__(512) void mlp_raw(
    const float* __restrict__ x,
    const float* __restrict__ w0, const float* __restrict__ b0,
    const float* __restrict__ w1, const float* __restrict__ b1,
    const float* __restrict__ w2, const float* __restrict__ b2,
    const float* __restrict__ ss, const float* __restrict__ rs,
    float* __restrict__ out) {
  __shared__ float red[256];
  const int tid  = threadIdx.x;
  const int wave = __builtin_amdgcn_readfirstlane(tid) >> 6;
  const int lane = tid & 63;
  const int half = wave >> 2;
  const int sub  = wave & 3;
  const int o     = blockIdx.x & (OUT_SZ - 1);
  const int chunk = blockIdx.x >> 7;
  const int b     = chunk * 256 + sub * 64 + lane;
  const int i0    = half * 64;
  const float4* __restrict__ xrow = (const float4*)(x + (size_t)b * IN_SZ + i0);
  float acc = 0.0f;
#pragma unroll 1
  for (int c = 0; c < 16; ++c) {
    float4 xv = xrow[c];
    float xs[4] = { xv.x, xv.y, xv.z, xv.w };
#pragma unroll
    for (int r = 0; r < 4; ++r) {
      int n = (i0 + c * 4 + r) * OUT_SZ + o;
      float h1[5], h2[5];
#pragma unroll
      for (int j = 0; j < 5; ++j)
        h1[j] = silu_f(fmaf(w0[n * 5 + j], xs[r], b0[n * 5 + j]));
#pragma unroll
      for (int j = 0; j < 5; ++j) {
        float z = b1[n * 5 + j];
#pragma unroll
        for (int k = 0; k < 5; ++k) z = fmaf(w1[n * 25 + j * 5 + k], h1[k], z);
        h2[j] = silu_f(z);
      }
      float y = b2[n];
#pragma unroll
      for (int k = 0; k < 5; ++k) y = fmaf(w2[n * 5 + k], h2[k], y);
      acc += fmaf(y, ss[n], xs[r] * rs[n]);
    }
  }
  if (half) red[sub * 64 + lane] = acc;
  __syncthreads();
  if (!half) out[(size_t)b * OUT_SZ + o] = acc + red[sub * 64 + lane];
}

extern "C" void kernel_launch(void* const* d_in, const int* in_sizes, int n_in,
                              void* d_out, int out_size, void* d_ws, size_t ws_size,
                              hipStream_t stream) {
  const float* x  = (const float*)d_in[0];
  const float* w0 = (const float*)d_in[1];
  const float* b0 = (const float*)d_in[2];
  const float* w1 = (const float*)d_in[3];
  const float* b1 = (const float*)d_in[4];
  const float* w2 = (const float*)d_in[5];
  const float* b2 = (const float*)d_in[6];
  const float* ss = (const float*)d_in[7];
  const float* rs = (const float*)d_in[8];

  const size_t TBL_BYTES = (size_t)NSUB * KNOTS * sizeof(__half2);  // 8 MiB

  if (ws_size >= TBL_BYTES) {
    __half2* tbl = (__half2*)d_ws;
    build_ikol<<<dim3(IN_SZ), dim3(1024), 0, stream>>>(
        w0, b0, w1, b1, w2, b2, ss, rs, tbl);
    mlp_scan<<<dim3(BATCH / 4), dim3(512), 0, stream>>>(
        x, tbl, (float*)d_out);
  } else {
    mlp_raw<<<dim3(OUT_SZ * (BATCH / 256)), dim3(512), 0, stream>>>(
        x, w0, b0, w1, b1, w2, b2, ss, rs, (float*)d_out);
  }
}